// Round 2
// baseline (127.384 us; speedup 1.0000x reference)
//
#include <hip/hip_runtime.h>
#include <hip/hip_bf16.h>
#include <math.h>

#define LOG2E 1.4426950408889634f

// ---------------------------------------------------------------------------
// Kernel 1: compress Z to uint8 in ws (Z in [1,95)) and zero the output
// (harness poisons d_out with 0xAA before every timed replay).
// ---------------------------------------------------------------------------
__global__ void __launch_bounds__(256)
zbl_prep(const int* __restrict__ Z, unsigned char* __restrict__ z8,
         float* __restrict__ out, int n_atoms, int out_n) {
    int i = blockIdx.x * blockDim.x + threadIdx.x;
    if (i < n_atoms) z8[i] = (unsigned char)Z[i];
    if (i < out_n)   out[i] = 0.0f;
}

// ---------------------------------------------------------------------------
// Kernel 2: per-pair ZBL + wave-64 segmented reduction (idx_i sorted).
// ZT = unsigned char (ws path) or int (fallback, gather raw atomic_numbers).
// za = Z^|a_exp| comes from a 96-entry LDS table (only 94 distinct Z values),
// so the only random global gather is 1 byte (or 4 in fallback) per side.
// ---------------------------------------------------------------------------
template <typename ZT>
__global__ void __launch_bounds__(256)
zbl_pairs(const float* __restrict__ dist, const float* __restrict__ cut,
          const int* __restrict__ idx_i, const int* __restrict__ idx_j,
          const ZT* __restrict__ zt,
          const float* __restrict__ a_coef, const float* __restrict__ a_exp,
          const float* __restrict__ phi_c, const float* __restrict__ phi_e,
          const float* __restrict__ ke, const float* __restrict__ d2a,
          const float* __restrict__ e2m,
          float* __restrict__ out, int n) {
    __shared__ float za_tab[128];

    // Wave-uniform parameters (scalar loads).
    float aexp   = fabsf(a_exp[0]);
    float inv_ac = __fdividef(1.0f, fabsf(a_coef[0]));
    float c0 = fabsf(phi_c[0]), c1 = fabsf(phi_c[1]),
          c2 = fabsf(phi_c[2]), c3 = fabsf(phi_c[3]);
    float cnorm = __fdividef(1.0f, c0 + c1 + c2 + c3);
    c0 *= cnorm; c1 *= cnorm; c2 *= cnorm; c3 *= cnorm;
    // exp(-e*x) = exp2(-(e*log2e)*x)
    float e0 = fabsf(phi_e[0]) * LOG2E, e1 = fabsf(phi_e[1]) * LOG2E,
          e2 = fabsf(phi_e[2]) * LOG2E, e3 = fabsf(phi_e[3]) * LOG2E;
    float scale = ke[0] * e2m[0];
    float inv_d2a = __fdividef(1.0f, d2a[0]);

    int t = threadIdx.x;
    if (t < 128) za_tab[t] = powf((float)t, aexp);  // 94 entries used
    __syncthreads();

    int p = blockIdx.x * blockDim.x + t;

    int   ii  = -1;
    float val = 0.0f;
    if (p < n) {
        ii = idx_i[p];                 // sorted -> near-uniform per wave
        int jj = idx_j[p];             // random
        int zi = (int)zt[ii];          // 1-B gather (broadcast-ish)
        int zj = (int)zt[jj];          // 1-B gather from 100 KB L2-resident table
        float zif = (float)zi, zjf = (float)zj;
        float d   = dist[p];
        float arg = d * (za_tab[zi] + za_tab[zj]) * inv_ac;
        float phi = c0 * exp2f(-e0 * arg) + c1 * exp2f(-e1 * arg)
                  + c2 * exp2f(-e2 * arg) + c3 * exp2f(-e3 * arg);
        float invd = __fdividef(1.0f, d);
        val = scale * zif * zjf * phi * cut[p] * invd * inv_d2a;
    }

    // Wave-64 segmented inclusive scan (equal idx_i contiguous). 6 rounds.
    int lane = t & 63;
    #pragma unroll
    for (int off = 1; off < 64; off <<= 1) {
        float ov = __shfl_up(val, (unsigned)off, 64);
        int   oi = __shfl_up(ii, (unsigned)off, 64);
        if (lane >= off && oi == ii) val += ov;
    }
    int nxt = __shfl_down(ii, 1u, 64);
    bool tail = (lane == 63) || (nxt != ii);
    if (p < n && tail) atomicAdd(out + ii, val);
}

extern "C" void kernel_launch(void* const* d_in, const int* in_sizes, int n_in,
                              void* d_out, int out_size, void* d_ws, size_t ws_size,
                              hipStream_t stream) {
    const int*   atomic_numbers = (const int*)  d_in[0];
    const float* distances      = (const float*)d_in[1];
    const float* cutoffs        = (const float*)d_in[2];
    const int*   idx_i          = (const int*)  d_in[3];
    const int*   idx_j          = (const int*)  d_in[4];
    const float* a_coefficient  = (const float*)d_in[5];
    const float* a_exponent     = (const float*)d_in[6];
    const float* phi_coeffs     = (const float*)d_in[7];
    const float* phi_exps       = (const float*)d_in[8];
    const float* ke             = (const float*)d_in[9];
    const float* d2a            = (const float*)d_in[10];
    const float* e2m            = (const float*)d_in[11];
    float* out = (float*)d_out;

    const int n_atoms = in_sizes[0];
    const int n_pairs = in_sizes[1];

    const int block = 256;
    const int grid_pairs = (n_pairs + block - 1) / block;
    const int grid_prep  = (((n_atoms > out_size) ? n_atoms : out_size) + block - 1) / block;

    if (ws_size >= (size_t)n_atoms) {
        unsigned char* z8 = (unsigned char*)d_ws;
        zbl_prep<<<grid_prep, block, 0, stream>>>(
            atomic_numbers, z8, out, n_atoms, out_size);
        zbl_pairs<unsigned char><<<grid_pairs, block, 0, stream>>>(
            distances, cutoffs, idx_i, idx_j, z8,
            a_coefficient, a_exponent, phi_coeffs, phi_exps, ke, d2a, e2m,
            out, n_pairs);
    } else {
        hipMemsetAsync(d_out, 0, (size_t)out_size * sizeof(float), stream);
        zbl_pairs<int><<<grid_pairs, block, 0, stream>>>(
            distances, cutoffs, idx_i, idx_j, atomic_numbers,
            a_coefficient, a_exponent, phi_coeffs, phi_exps, ke, d2a, e2m,
            out, n_pairs);
    }
}

// Round 3
// 122.291 us; speedup vs baseline: 1.0416x; 1.0416x over previous
//
#include <hip/hip_runtime.h>
#include <hip/hip_bf16.h>
#include <math.h>

#define LOG2E 1.4426950408889634f

// ---------------------------------------------------------------------------
// Kernel 1: compress Z to uint8 in ws (Z in [1,95)) and zero the output
// (harness poisons d_out with 0xAA before every timed replay).
// ---------------------------------------------------------------------------
__global__ void __launch_bounds__(256)
zbl_prep(const int* __restrict__ Z, unsigned char* __restrict__ z8,
         float* __restrict__ out, int n_atoms, int out_n) {
    int i = blockIdx.x * blockDim.x + threadIdx.x;
    if (i < n_atoms) z8[i] = (unsigned char)Z[i];
    if (i < out_n)   out[i] = 0.0f;
}

// ---------------------------------------------------------------------------
// Kernel 2: 2 pairs per thread. Streaming loads are dwordx2; Z gathers are
// 1 byte from the 100 KB L2-resident z8 table; za = Z^|a_exp| from a 128-entry
// LDS table. Segmented reduction: thread-local combine + one wave-64
// segmented scan over the per-thread tail values + boundary-correct commits.
// idx_i is globally sorted, so equal keys are contiguous in lane order.
// ---------------------------------------------------------------------------
__global__ void __launch_bounds__(256)
zbl_pairs2(const float* __restrict__ dist, const float* __restrict__ cut,
           const int* __restrict__ idx_i, const int* __restrict__ idx_j,
           const unsigned char* __restrict__ z8,
           const float* __restrict__ a_coef, const float* __restrict__ a_exp,
           const float* __restrict__ phi_c, const float* __restrict__ phi_e,
           const float* __restrict__ ke, const float* __restrict__ d2a,
           const float* __restrict__ e2m,
           float* __restrict__ out, int n) {
    __shared__ float za_tab[128];

    // Wave-uniform parameters (scalar loads).
    float aexp   = fabsf(a_exp[0]);
    float inv_ac = __fdividef(1.0f, fabsf(a_coef[0]));
    float c0 = fabsf(phi_c[0]), c1 = fabsf(phi_c[1]),
          c2 = fabsf(phi_c[2]), c3 = fabsf(phi_c[3]);
    float cnorm = __fdividef(1.0f, c0 + c1 + c2 + c3);
    c0 *= cnorm; c1 *= cnorm; c2 *= cnorm; c3 *= cnorm;
    // exp(-e*x) = exp2(-(e*log2e)*x)
    float e0 = fabsf(phi_e[0]) * LOG2E, e1 = fabsf(phi_e[1]) * LOG2E,
          e2 = fabsf(phi_e[2]) * LOG2E, e3 = fabsf(phi_e[3]) * LOG2E;
    float scale = ke[0] * e2m[0] * __fdividef(1.0f, d2a[0]);

    int t = threadIdx.x;
    if (t < 128) za_tab[t] = (t >= 1) ? exp2f(aexp * __log2f((float)t)) : 0.0f;
    __syncthreads();

    int gid = blockIdx.x * blockDim.x + t;
    int p0 = 2 * gid, p1 = p0 + 1;

    int   k0 = -1, k1 = -1;
    float v0 = 0.0f, v1 = 0.0f;

    if (p1 < n) {
        // full 2-pair path: vector loads
        float2 d2 = ((const float2*)dist)[gid];
        float2 c2v = ((const float2*)cut)[gid];
        int2   i2 = ((const int2*)idx_i)[gid];
        int2   j2 = ((const int2*)idx_j)[gid];
        k0 = i2.x; k1 = i2.y;
        int zi0 = (int)z8[k0],  zi1 = (int)z8[k1];
        int zj0 = (int)z8[j2.x], zj1 = (int)z8[j2.y];

        float arg0 = d2.x * (za_tab[zi0] + za_tab[zj0]) * inv_ac;
        float arg1 = d2.y * (za_tab[zi1] + za_tab[zj1]) * inv_ac;
        float phi0 = c0 * exp2f(-e0 * arg0) + c1 * exp2f(-e1 * arg0)
                   + c2 * exp2f(-e2 * arg0) + c3 * exp2f(-e3 * arg0);
        float phi1 = c0 * exp2f(-e0 * arg1) + c1 * exp2f(-e1 * arg1)
                   + c2 * exp2f(-e2 * arg1) + c3 * exp2f(-e3 * arg1);
        v0 = scale * (float)(zi0 * zj0) * phi0 * c2v.x * __fdividef(1.0f, d2.x);
        v1 = scale * (float)(zi1 * zj1) * phi1 * c2v.y * __fdividef(1.0f, d2.y);
    } else if (p0 < n) {
        // odd tail: one pair
        k0 = idx_i[p0];
        int jj = idx_j[p0];
        int zi = (int)z8[k0], zj = (int)z8[jj];
        float d = dist[p0];
        float arg = d * (za_tab[zi] + za_tab[zj]) * inv_ac;
        float phi = c0 * exp2f(-e0 * arg) + c1 * exp2f(-e1 * arg)
                  + c2 * exp2f(-e2 * arg) + c3 * exp2f(-e3 * arg);
        v0 = scale * (float)(zi * zj) * phi * cut[p0] * __fdividef(1.0f, d);
    }

    // c = contribution of this thread to the segment containing its LAST elem.
    float c = v1 + ((k0 == k1) ? v0 : 0.0f);
    int   key = k1;

    // Wave-64 segmented inclusive scan over (key, c).
    int lane = t & 63;
    #pragma unroll
    for (int off = 1; off < 64; off <<= 1) {
        float ov = __shfl_up(c, (unsigned)off, 64);
        int   ok = __shfl_up(key, (unsigned)off, 64);
        if (lane >= off && ok == key) c += ov;
    }

    // Neighbor info for boundary commits.
    float prev_c   = __shfl_up(c, 1u, 64);
    int   prev_key = __shfl_up(key, 1u, 64);
    int   next_k0  = __shfl_down(k0, 1u, 64);

    // Commit elem0's segment if it ends inside this thread (k0 != k1).
    if (k0 >= 0 && k0 != k1) {
        float tot = v0 + ((lane > 0 && prev_key == k0) ? prev_c : 0.0f);
        atomicAdd(out + k0, tot);
    }
    // Commit the last-elem segment at its tail lane.
    bool tail = (lane == 63) || (next_k0 != key);
    if (key >= 0 && tail) atomicAdd(out + key, c);
}

extern "C" void kernel_launch(void* const* d_in, const int* in_sizes, int n_in,
                              void* d_out, int out_size, void* d_ws, size_t ws_size,
                              hipStream_t stream) {
    const int*   atomic_numbers = (const int*)  d_in[0];
    const float* distances      = (const float*)d_in[1];
    const float* cutoffs        = (const float*)d_in[2];
    const int*   idx_i          = (const int*)  d_in[3];
    const int*   idx_j          = (const int*)  d_in[4];
    const float* a_coefficient  = (const float*)d_in[5];
    const float* a_exponent     = (const float*)d_in[6];
    const float* phi_coeffs     = (const float*)d_in[7];
    const float* phi_exps       = (const float*)d_in[8];
    const float* ke             = (const float*)d_in[9];
    const float* d2a            = (const float*)d_in[10];
    const float* e2m            = (const float*)d_in[11];
    float* out = (float*)d_out;

    const int n_atoms = in_sizes[0];
    const int n_pairs = in_sizes[1];

    const int block = 256;
    const int n_threads = (n_pairs + 1) / 2;
    const int grid_pairs = (n_threads + block - 1) / block;
    const int grid_prep  = (((n_atoms > out_size) ? n_atoms : out_size) + block - 1) / block;

    // ws_size is ample (harness scratch); z8 needs only n_atoms bytes.
    unsigned char* z8 = (unsigned char*)d_ws;
    zbl_prep<<<grid_prep, block, 0, stream>>>(
        atomic_numbers, z8, out, n_atoms, out_size);
    zbl_pairs2<<<grid_pairs, block, 0, stream>>>(
        distances, cutoffs, idx_i, idx_j, z8,
        a_coefficient, a_exponent, phi_coeffs, phi_exps, ke, d2a, e2m,
        out, n_pairs);
}